// Round 10
// baseline (172.615 us; speedup 1.0000x reference)
//
#include <hip/hip_runtime.h>
#include <stdint.h>

#define DEV __device__ __forceinline__

typedef __attribute__((ext_vector_type(4))) float f32x4;
typedef __attribute__((ext_vector_type(16))) float f32x16;
typedef __attribute__((ext_vector_type(8))) __bf16 bf16x8;
typedef __attribute__((ext_vector_type(4))) __bf16 bf16x4;
typedef __attribute__((ext_vector_type(8))) short short8;
typedef __attribute__((ext_vector_type(4))) unsigned short u16x4;
typedef __attribute__((ext_vector_type(2))) unsigned int u32x2;
typedef __attribute__((ext_vector_type(4))) unsigned int u32x4;

DEV unsigned short f2bf_n(float f) {
    __bf16 h = (__bf16)f;
    return __builtin_bit_cast(unsigned short, h);
}
DEV bf16x8 ld8(const unsigned short* p) {
    short8 v = *(const short8*)p;
    return __builtin_bit_cast(bf16x8, v);
}
DEV void ldsdma16(unsigned short* lds, const unsigned short* g) {
    __builtin_amdgcn_global_load_lds(
        (const __attribute__((address_space(1))) unsigned int*)g,
        (__attribute__((address_space(3))) unsigned int*)lds, 16, 0, 0);
}

// ---------------------------------------------------------------------------
// Fused compact + W-convert + out-init. Grid 8194 blocks:
//   0-1          token compaction scan
//   2..4097      W f32->bf16 (Wq|Wk|Wv|Wo)
//   4098..8193   out init: MASKED tokens get out row = bo
// ---------------------------------------------------------------------------
__global__ __launch_bounds__(256) void compact_kernel(
    const float* __restrict__ mask,
    const float* __restrict__ Wq, const float* __restrict__ Wk,
    const float* __restrict__ Wv, const float* __restrict__ Wo,
    const float* __restrict__ bo,
    int* __restrict__ sidx, int* __restrict__ hdr,
    unsigned short* __restrict__ Wb, float* __restrict__ out)
{
    const int t = threadIdx.x;
    if (blockIdx.x >= 4098) {
        int row = blockIdx.x - 4098;
        int b = row >> 11, s = row & 2047;
        if (mask[b * 2048 + s] > 0.5f) return;   // oproj writes this row fully
        int e = t * 4;
        f32x4 v = *(const f32x4*)&bo[e];
        *(f32x4*)&out[(size_t)row * 1024 + e] = v;
        return;
    }
    if (blockIdx.x >= 2) {
        int c = (blockIdx.x - 2) * 256 + t;
        int wsel = c >> 18, off = (c & 262143) * 4;
        const float* ws_[4] = { Wq, Wk, Wv, Wo };
        f32x4 v = *(const f32x4*)(ws_[wsel] + off);
        bf16x4 b = { (__bf16)v[0], (__bf16)v[1], (__bf16)v[2], (__bf16)v[3] };
        *(bf16x4*)&Wb[wsel * 1048576 + off] = b;
        return;
    }
    __shared__ int part[256];
    const int b = blockIdx.x;
    int loc[8], cnt = 0;
#pragma unroll
    for (int k = 0; k < 8; ++k) {
        loc[k] = (mask[b * 2048 + t * 8 + k] > 0.5f) ? 1 : 0;
        cnt += loc[k];
    }
    part[t] = cnt;
    __syncthreads();
#pragma unroll
    for (int off = 1; off < 256; off <<= 1) {
        int v = (t >= off) ? part[t - off] : 0;
        __syncthreads();
        part[t] += v;
        __syncthreads();
    }
    const int total = part[255];
    if (t == 0) {
        hdr[b] = total;
        hdr[2 + b] = (total + 127) & ~127;
    }
    int base = part[t] - cnt;            // exclusive prefix
#pragma unroll
    for (int k = 0; k < 8; ++k)
        if (loc[k]) sidx[b * 2048 + (base++)] = t * 8 + k;
    for (int j = total + t; j < 2048; j += 256) sidx[b * 2048 + j] = -1;
}

// ---------------------------------------------------------------------------
// Fused QKV projection v11b: prep's gather absorbed. A-tile reg-staged
// directly from f32 X via sidx (2x global_load_dwordx4 -> bf16 cast ->
// 16B LDS store per inst; pad rows zero-masked).
// BUGFIX vs v11: sidx index is m0+row (m0 ALREADY contains b*2048; v11's
// extra b*2048 read past the array for batch 1 -> absmax 5.9e-2).
// Counted-vmcnt ledger: prologue {A0:4,B0:2,A1:4,B1:2}=12, vmcnt(8) drains
// A0, writeA(0); iter kt: loadA(kt+2) -> 12; vmcnt(6) drains B(kt)+A(kt+1);
// compute; stageB(kt+2); writeA(A(kt+1)->cur^1). Epilogue vmcnt(2)/(0).
// Two A-reg tiles parity-selected by kt&1 (static indexing). 64x64 tiles,
// 32 KB dbuf. grid (64, 48), 256 thr.
// ---------------------------------------------------------------------------
__global__ __launch_bounds__(256, 4) void qkv_kernel(
    const float* __restrict__ X, const unsigned short* __restrict__ Wb,
    const float* __restrict__ bq, const float* __restrict__ bk,
    const float* __restrict__ bv, const int* __restrict__ sidx,
    const int* __restrict__ hdr,
    unsigned short* __restrict__ Qc, unsigned short* __restrict__ Kc,
    unsigned short* __restrict__ VTc)
{
    __shared__ __align__(16) unsigned short SMEM[16384];   // 32 KB

    const int ln = blockIdx.y * 64 + blockIdx.x;   // 3072 blocks
    const int xcd = ln & 7, idx = ln >> 3;
    const int wy = xcd * 6 + idx % 6;               // 0..47
    const int wx = idx / 6;                         // 0..63

    const int m0 = wx * 64;                         // GLOBAL compact row
    const int b = m0 >> 11;
    if ((m0 & 2047) >= hdr[2 + b]) return;

    const int t = threadIdx.x;
    const int lane = t & 63, w = t >> 6;
    const int l15 = lane & 15, grp = lane >> 4;
    const int which = wy >> 4;                      // 0..2
    const int e0 = (wy & 15) * 64;

    const unsigned short* Wmat = Wb + which * 1048576;
    const float* bias = (which == 0) ? bq : (which == 1) ? bk : bv;

    const int srow = lane >> 3, sc_ = lane & 7;

    // per-lane A source pointers (row via sidx, col pre-swizzled)
    const float* abase[2];
    unsigned short amask[2];
#pragma unroll
    for (int jj = 0; jj < 2; ++jj) {
        int inst = w * 2 + jj;
        int row = inst * 8 + srow;
        int s = sidx[m0 + row];                     // m0 already has b*2048
        amask[jj] = (s >= 0) ? (unsigned short)0xFFFF : (unsigned short)0;
        int sc = (s >= 0 && s < 2048) ? s : 0;
        int cs = sc_ ^ (row & 7);
        abase[jj] = &X[(size_t)(b * 2048 + sc) * 1024 + cs * 8];
    }

    f32x4 acc[4];
#pragma unroll
    for (int i = 0; i < 4; ++i) acc[i] = (f32x4){0.f, 0.f, 0.f, 0.f};

    auto loadA = [&](int kt, f32x4* ar) {
        const int k0 = kt * 64;
#pragma unroll
        for (int jj = 0; jj < 2; ++jj) {
            const float* p = abase[jj] + k0;
            ar[jj * 2]     = *(const f32x4*)p;
            ar[jj * 2 + 1] = *(const f32x4*)(p + 4);
        }
    };
    auto writeA = [&](int pbuf, const f32x4* ar) {
        unsigned short* As = SMEM + pbuf * 8192;
#pragma unroll
        for (int jj = 0; jj < 2; ++jj) {
            short8 pv;
#pragma unroll
            for (int q = 0; q < 4; ++q) {
                pv[q]     = (short)(f2bf_n(ar[jj*2][q])     & amask[jj]);
                pv[4 + q] = (short)(f2bf_n(ar[jj*2+1][q])   & amask[jj]);
            }
            int inst = w * 2 + jj;
            *(short8*)&As[inst * 512 + lane * 8] = pv;
        }
    };
    auto stageB = [&](int p, int kt) {
        const int k0 = kt * 64;
        unsigned short* Bs = SMEM + p * 8192 + 4096;
#pragma unroll
        for (int jj = 0; jj < 2; ++jj) {
            int inst = w * 2 + jj;
            int row = inst * 8 + srow;
            int cs = sc_ ^ (row & 7);
            ldsdma16(&Bs[inst * 512], &Wmat[(e0 + row) * 1024 + k0 + cs * 8]);
        }
    };

    f32x4 aA[4], aB[4];
    loadA(0, aA);
    stageB(0, 0);
    loadA(1, aB);
    stageB(1, 1);
    asm volatile("s_waitcnt vmcnt(8)" ::: "memory");
    writeA(0, aA);                                  // A(0) -> buf0; aA free

    int cur = 0;
    for (int kt = 0; kt < 16; ++kt) {
        if (kt < 14) {
            if (kt & 1) loadA(kt + 2, aB);
            else        loadA(kt + 2, aA);
        }
        if (kt < 14)       asm volatile("s_waitcnt vmcnt(6) lgkmcnt(0)" ::: "memory");
        else if (kt == 14) asm volatile("s_waitcnt vmcnt(2) lgkmcnt(0)" ::: "memory");
        else               asm volatile("s_waitcnt vmcnt(0) lgkmcnt(0)" ::: "memory");
        __builtin_amdgcn_s_barrier();
        const unsigned short* As = SMEM + cur * 8192;
        const unsigned short* Bs = As + 4096;
#pragma unroll
        for (int kk = 0; kk < 64; kk += 32) {
            const int cb = kk >> 3;
            bf16x8 af[4], bfr;
#pragma unroll
            for (int i = 0; i < 4; ++i) {
                int r = i * 16 + l15;
                af[i] = ld8(&As[r * 64 + (((cb + grp) ^ (r & 7)) << 3)]);
            }
            {
                int r = w * 16 + l15;
                bfr = ld8(&Bs[r * 64 + (((cb + grp) ^ (r & 7)) << 3)]);
            }
            __builtin_amdgcn_s_setprio(1);
#pragma unroll
            for (int i = 0; i < 4; ++i)
                acc[i] = __builtin_amdgcn_mfma_f32_16x16x32_bf16(
                    af[i], bfr, acc[i], 0, 0, 0);
            __builtin_amdgcn_s_setprio(0);
        }
        __builtin_amdgcn_s_barrier();
        if (kt + 2 < 16) stageB(cur, kt + 2);       // tile kt+2 -> retired buf
        if (kt + 1 < 16) {                          // A(kt+1) -> buf cur^1
            if (kt & 1) writeA(cur ^ 1, aA);
            else        writeA(cur ^ 1, aB);
        }
        cur ^= 1;
    }

    const int h = e0 >> 6;                 // single head per 64-slice
    if (which == 2) {
        // stage transposed into SMEM[col][row], stride 72 (pad 8)
        {
            int e = e0 + w * 16 + l15;
            float bv_ = bias[e];
#pragma unroll
            for (int i = 0; i < 4; ++i) {
                u16x4 pk;
#pragma unroll
                for (int r = 0; r < 4; ++r) pk[r] = f2bf_n(acc[i][r] + bv_);
                *(u16x4*)&SMEM[(w * 16 + l15) * 72 + i * 16 + grp * 4] = pk;
            }
        }
        __syncthreads();
        const int s0 = m0 & 2047;
#pragma unroll
        for (int round = 0; round < 2; ++round) {
            int dhl = (t >> 3) + round * 32;   // 0..63 (dh)
            int chunk = t & 7;                 // s chunk
            *(short8*)&VTc[((b * 16 + h) * 64 + dhl) * 2048 + s0 + chunk * 8] =
                *(const short8*)&SMEM[dhl * 72 + chunk * 8];
        }
    } else {
        const float scale = (which == 0) ? 0.125f : 1.0f;
        {
            int e = e0 + w * 16 + l15;
            float bv_ = bias[e];
#pragma unroll
            for (int i = 0; i < 4; ++i)
#pragma unroll
                for (int r = 0; r < 4; ++r)
                    SMEM[(i * 16 + grp * 4 + r) * 72 + w * 16 + l15] =
                        f2bf_n((acc[i][r] + bv_) * scale);
        }
        __syncthreads();
        unsigned short* dst = (which == 0) ? Qc : Kc;
#pragma unroll
        for (int round = 0; round < 2; ++round) {
            int tl = (t >> 3) + round * 32;    // row (s offset)
            int chunk = t & 7;                 // dh chunk
            int s = (m0 & 2047) + tl;
            *(short8*)&dst[((b * 16 + h) * 2048 + s) * 64 + chunk * 8] =
                *(const short8*)&SMEM[tl * 72 + chunk * 8];
        }
    }
}

// ---------------------------------------------------------------------------
// Flash attention (unchanged): v8 staged loop + XCD co-location.
// grid (16, 32), 512 thr. LDS 64 KB.
// ---------------------------------------------------------------------------
__global__ __launch_bounds__(512, 4) void attn_kernel(
    const unsigned short* __restrict__ Qc, const unsigned short* __restrict__ Kc,
    const unsigned short* __restrict__ VTc, const int* __restrict__ hdr,
    unsigned short* __restrict__ Xattn)
{
    __shared__ __align__(16) unsigned short SMEM[32768];   // 64 KB
    float* mrg = (float*)SMEM;

    const int ln = blockIdx.y * 16 + blockIdx.x;
    const int qb = (ln >> 3) & 15;
    const int bh = ((ln >> 7) << 3) | (ln & 7);
    const int b = bh >> 4;
    const int nbl = hdr[b], nbpl = hdr[2 + b];
    const int q0 = qb * 128;
    if (q0 >= nbpl) return;

    const int t = threadIdx.x;
    const int lane = t & 63, w = t >> 6;
    const int l31 = lane & 31, half = lane >> 5;
    const int qg = w & 3, khalf = w >> 2;

    const unsigned short* Kp = Kc + (size_t)bh * 131072;
    const unsigned short* Vp = VTc + (size_t)bh * 131072;

    bf16x8 qf[4];
#pragma unroll
    for (int s = 0; s < 4; ++s)
        qf[s] = ld8(&Qc[(bh * 2048 + q0 + qg * 32 + l31) * 64 + s * 16 + half * 8]);

    f32x16 accd[2];
    float lsum = 0.f;
#pragma unroll
    for (int d = 0; d < 2; ++d)
#pragma unroll
        for (int r = 0; r < 16; ++r) accd[d][r] = 0.f;

    auto stageKV = [&](int p, int kb) {
        const int k0 = kb * 128;
        unsigned short* Ks = SMEM + p * 16384;
        unsigned short* Vs = Ks + 8192;
#pragma unroll
        for (int ii = 0; ii < 2; ++ii) {
            int inst = w * 2 + ii;
            int row = inst * 8 + (lane >> 3);
            int cs = (lane & 7) ^ (row & 7);
            ldsdma16(&Ks[inst * 512], &Kp[(k0 + row) * 64 + cs * 8]);
        }
#pragma unroll
        for (int ii = 0; ii < 2; ++ii) {
            int inst = w * 2 + ii;
            int row = inst * 4 + (lane >> 4);
            int cs = (lane & 15) ^ (row & 15);
            ldsdma16(&Vs[inst * 512], &Vp[row * 2048 + k0 + cs * 8]);
        }
    };

    const int nkb = nbpl >> 7;
    stageKV(0, 0);
    if (nkb > 1) stageKV(1, 1);
    int cur = 0;
    for (int kb = 0; kb < nkb; ++kb) {
        const int k0 = kb * 128;
        if (kb < nkb - 2) asm volatile("s_waitcnt vmcnt(4)" ::: "memory");
        else              asm volatile("s_waitcnt vmcnt(0)" ::: "memory");
        __builtin_amdgcn_s_barrier();
        const unsigned short* Ks = SMEM + cur * 16384;
        const unsigned short* Vs = Ks + 8192;

#pragma unroll
        for (int g = 0; g < 2; ++g) {
            f32x16 z;
#pragma unroll
            for (int r = 0; r < 16; ++r) z[r] = 0.f;
            int rK = khalf * 64 + g * 32 + l31;
            __builtin_amdgcn_s_setprio(1);
#pragma unroll
            for (int s = 0; s < 4; ++s) {
                int chunk = s * 2 + half;
                bf16x8 kf = ld8(&Ks[rK * 64 + ((chunk ^ (rK & 7)) << 3)]);
                z = __builtin_amdgcn_mfma_f32_32x32x16_bf16(kf, qf[s], z, 0, 0, 0);
            }
            __builtin_amdgcn_s_setprio(0);
            const int rem = nbl - (k0 + khalf * 64 + g * 32);
#pragma unroll
            for (int r = 0; r < 16; ++r) z[r] = __expf(z[r]);
            if (rem < 32) {
#pragma unroll
                for (int r = 0; r < 16; ++r) {
                    int kr = (r & 3) + 8 * (r >> 2) + 4 * half;
                    if (kr >= rem) z[r] = 0.f;
                }
            }
#pragma unroll
            for (int r = 0; r < 16; ++r) lsum += z[r];

            unsigned int wd[8];
#pragma unroll
            for (int j = 0; j < 8; ++j)
                asm("v_cvt_pk_bf16_f32 %0, %1, %2"
                    : "=v"(wd[j]) : "v"(z[2 * j]), "v"(z[2 * j + 1]));
            {
                u32x2 r0 = __builtin_amdgcn_permlane32_swap(wd[0], wd[2], false, false);
                wd[0] = r0[0]; wd[2] = r0[1];
                u32x2 r1 = __builtin_amdgcn_permlane32_swap(wd[1], wd[3], false, false);
                wd[1] = r1[0]; wd[3] = r1[1];
                u32x2 r2 = __builtin_amdgcn_permlane32_swap(wd[4], wd[6], false, false);
                wd[4] = r2[0]; wd[6] = r2[1];
                u32x2 r3 = __builtin_amdgcn_permlane32_swap(wd[5], wd[7], false, false);
                wd[5] = r3[0]; wd[7] = r3[1];
            }
            bf16x8 pf[2];
            pf[0] = __builtin_bit_cast(bf16x8, (u32x4){wd[0], wd[1], wd[2], wd[3]});
            pf[1] = __builtin_bit_cast(bf16x8, (u32x4){wd[4], wd[5], wd[6], wd[7]});

            __builtin_amdgcn_s_setprio(1);
#pragma unroll
            for (int d = 0; d < 2; ++d) {
                int rV = d * 32 + l31;
#pragma unroll
                for (int sp = 0; sp < 2; ++sp) {
                    int chunk = khalf * 8 + g * 4 + sp * 2 + half;
                    bf16x8 vf = ld8(&Vs[rV * 128 + ((chunk ^ (rV & 15)) << 3)]);
                    accd[d] = __builtin_amdgcn_mfma_f32_32x32x16_bf16(
                        pf[sp], vf, accd[d], 0, 0, 0);
                }
            }
            __builtin_amdgcn_s_setprio(0);
        }
        __builtin_amdgcn_s_barrier();
        if (kb + 2 < nkb) stageKV(cur, kb + 2);
        cur ^= 1;
    }

    lsum += __shfl_xor(lsum, 32, 64);

    float* q_ = mrg + qg * 2080;
    if (khalf == 1) {
#pragma unroll
        for (int r = 0; r < 16; ++r) {
            q_[(r) * 64 + lane]      = accd[0][r];
            q_[(16 + r) * 64 + lane] = accd[1][r];
        }
        if (half == 0) q_[2048 + l31] = lsum;
    }
    __syncthreads();
    if (khalf == 0) {
#pragma unroll
        for (int r = 0; r < 16; ++r) {
            accd[0][r] += q_[(r) * 64 + lane];
            accd[1][r] += q_[(16 + r) * 64 + lane];
        }
        float tot = lsum + q_[2048 + l31];
#pragma unroll
        for (int r = 0; r < 16; ++r) {
            int ql = (r & 3) + 8 * (r >> 2) + 4 * half;
            int j = q0 + qg * 32 + ql;
            float lr = __shfl(tot, ql, 64);
            float inv = 1.f / (lr + 1e-13f);
#pragma unroll
            for (int d = 0; d < 2; ++d)
                Xattn[(b * 2048 + j) * 1024 + (bh & 15) * 64 + d * 32 + l31] =
                    f2bf_n(accd[d][r] * inv);
        }
    }
}

// ---------------------------------------------------------------------------
// Output projection (unchanged): 64x64 core, 32 KB dbuf, vmcnt(4) depth-2.
// grid (64, 16), 256 thr.
// ---------------------------------------------------------------------------
__global__ __launch_bounds__(256, 5) void oproj_kernel(
    const unsigned short* __restrict__ A, const unsigned short* __restrict__ W,
    const float* __restrict__ bias, const int* __restrict__ sidx,
    const int* __restrict__ hdr, float* __restrict__ out)
{
    __shared__ __align__(16) unsigned short SMEM[16384];   // 32 KB

    const int ln = blockIdx.y * 64 + blockIdx.x;   // 1024 blocks
    const int xcd = ln & 7, idx = ln >> 3;
    const int wy = xcd * 2 + (idx & 1);             // 0..15
    const int wx = idx >> 1;                        // 0..63

    const int m0 = wx * 64;
    const int b = m0 >> 11;
    const int nbl = hdr[b];
    if ((m0 & 2047) >= hdr[2 + b]) return;

    const int t = threadIdx.x;
    const int lane = t & 63, w = t >> 6;
    const int l15 = lane & 15, grp = lane >> 4;
    const int e0 = wy * 64;
    const int srow = lane >> 3, sc_ = lane & 7;

    f32x4 acc[4];
#pragma unroll
    for (int i = 0; i < 4; ++i) acc[i] = (f32x4){0.f, 0.f, 0.f, 0.f};

    auto stage = [&](int p, int kt) {
        const int k0 = kt * 64;
        unsigned short* As = SMEM + p * 8192;
        unsigned short* Bs = As + 4096;
#pragma unroll
        for (int jj = 0; jj < 2; ++jj) {
            int inst = w * 2 + jj;
            int row = inst * 8 + srow;
            int cs = sc_ ^ (row & 7);
            ldsdma16(&As[inst * 512], &A[(m0 + row) * 1024 + k0 + cs * 8]);
        }
#pragma unroll
        for (int jj = 0; jj < 2; ++jj) {
            int inst = w * 2 + jj;
            int row = inst * 8 + srow;
            int cs = sc_ ^ (row & 7);
            ldsdma16(&Bs[inst * 512], &W[(e0 + row) * 1024 + k0 + cs * 8]);
        }
    };

    stage(0, 0);
    stage(1, 1);
    int cur = 0;
    for (int kt = 0; kt < 16; ++kt) {
        if (kt < 14) asm volatile("s_waitcnt vmcnt(4)" ::: "memory");
        else         asm volatile("s_waitcnt vmcnt(0)" ::: "memory");
        __builtin_amdgcn_s_barrier();
        const unsigned short* As = SMEM + cur * 8192;
        const unsigned short* Bs = As + 4096;
#pragma unroll
        for (int kk = 0; kk < 64; kk += 32) {
            const int cb = kk >> 3;
            bf16x8 af[4], bfr;
#pragma unroll
            for (int i = 0; i < 4; ++i) {
                int r = i * 16 + l15;
                af[i] = ld8(&As[r * 64 + (((cb + grp) ^ (r & 7)) << 3)]);
            }
            {
                int r = w * 16 + l15;
                bfr = ld8(&Bs[r * 64 + (((cb + grp) ^ (r & 7)) << 3)]);
            }
            __builtin_amdgcn_s_setprio(1);
#pragma unroll
            for (int i = 0; i < 4; ++i)
                acc[i] = __builtin_amdgcn_mfma_f32_16x16x32_bf16(
                    af[i], bfr, acc[i], 0, 0, 0);
            __builtin_amdgcn_s_setprio(0);
        }
        __builtin_amdgcn_s_barrier();
        if (kt + 2 < 16) stage(cur, kt + 2);
        cur ^= 1;
    }

    {
        int e = e0 + w * 16 + l15;
        float bv_ = bias[e];
#pragma unroll
        for (int i = 0; i < 4; ++i)
#pragma unroll
            for (int r = 0; r < 4; ++r) {
                int jl = (m0 & 2047) + i * 16 + grp * 4 + r;
                if (jl < nbl) {
                    int s = sidx[b * 2048 + jl];
                    out[(size_t)(b * 2048 + s) * 1024 + e] = acc[i][r] + bv_;
                }
            }
    }
}

extern "C" void kernel_launch(void* const* d_in, const int* in_sizes, int n_in,
                              void* d_out, int out_size, void* d_ws, size_t ws_size,
                              hipStream_t stream) {
    const float* x    = (const float*)d_in[0];
    const float* mask = (const float*)d_in[1];
    const float* Wq   = (const float*)d_in[2];
    const float* bq   = (const float*)d_in[3];
    const float* Wk   = (const float*)d_in[4];
    const float* bk   = (const float*)d_in[5];
    const float* Wv   = (const float*)d_in[6];
    const float* bv   = (const float*)d_in[7];
    const float* Wo   = (const float*)d_in[8];
    const float* bo   = (const float*)d_in[9];
    float* out = (float*)d_out;

    unsigned short* Qc   = (unsigned short*)d_ws;    // u16 element offsets:
    unsigned short* Kc   = Qc + 4194304;
    unsigned short* VTc  = Qc + 8388608;
    unsigned short* Xa   = Qc + 12582912;            // Xattn (attn -> oproj)
    unsigned short* Wb   = Qc + 16777216;
    int* sidx            = (int*)(Qc + 20971520);    // 4096 ints
    int* hdr             = sidx + 4096;              // nb[2], nbp[2]

    compact_kernel<<<dim3(8194), 256, 0, stream>>>(mask, Wq, Wk, Wv, Wo, bo,
                                                   sidx, hdr, Wb, out);
    qkv_kernel<<<dim3(64, 48), 256, 0, stream>>>(x, Wb, bq, bk, bv, sidx, hdr,
                                                 Qc, Kc, VTc);
    attn_kernel<<<dim3(16, 32), 512, 0, stream>>>(Qc, Kc, VTc, hdr, Xa);
    oproj_kernel<<<dim3(64, 16), 256, 0, stream>>>(Xa, Wb + 3145728, bo,
                                                   sidx, hdr, out);
}

// Round 11
// 163.165 us; speedup vs baseline: 1.0579x; 1.0579x over previous
//
#include <hip/hip_runtime.h>
#include <stdint.h>

#define DEV __device__ __forceinline__

typedef __attribute__((ext_vector_type(4))) float f32x4;
typedef __attribute__((ext_vector_type(16))) float f32x16;
typedef __attribute__((ext_vector_type(8))) __bf16 bf16x8;
typedef __attribute__((ext_vector_type(4))) __bf16 bf16x4;
typedef __attribute__((ext_vector_type(8))) short short8;
typedef __attribute__((ext_vector_type(4))) unsigned short u16x4;
typedef __attribute__((ext_vector_type(2))) unsigned int u32x2;
typedef __attribute__((ext_vector_type(4))) unsigned int u32x4;

DEV unsigned short f2bf_n(float f) {
    __bf16 h = (__bf16)f;
    return __builtin_bit_cast(unsigned short, h);
}
DEV bf16x8 ld8(const unsigned short* p) {
    short8 v = *(const short8*)p;
    return __builtin_bit_cast(bf16x8, v);
}
DEV void ldsdma16(unsigned short* lds, const unsigned short* g) {
    __builtin_amdgcn_global_load_lds(
        (const __attribute__((address_space(1))) unsigned int*)g,
        (__attribute__((address_space(3))) unsigned int*)lds, 16, 0, 0);
}

// ---------------------------------------------------------------------------
// Fused compact + W-convert (R7 form). Blocks 0-1: scan; 2..4097: W->bf16.
// ---------------------------------------------------------------------------
__global__ __launch_bounds__(256) void compact_kernel(
    const float* __restrict__ mask,
    const float* __restrict__ Wq, const float* __restrict__ Wk,
    const float* __restrict__ Wv, const float* __restrict__ Wo,
    int* __restrict__ sidx, int* __restrict__ hdr,
    unsigned short* __restrict__ Wb)
{
    const int t = threadIdx.x;
    if (blockIdx.x >= 2) {
        int c = (blockIdx.x - 2) * 256 + t;
        int wsel = c >> 18, off = (c & 262143) * 4;
        const float* ws_[4] = { Wq, Wk, Wv, Wo };
        f32x4 v = *(const f32x4*)(ws_[wsel] + off);
        bf16x4 b = { (__bf16)v[0], (__bf16)v[1], (__bf16)v[2], (__bf16)v[3] };
        *(bf16x4*)&Wb[wsel * 1048576 + off] = b;
        return;
    }
    __shared__ int part[256];
    const int b = blockIdx.x;
    int loc[8], cnt = 0;
#pragma unroll
    for (int k = 0; k < 8; ++k) {
        loc[k] = (mask[b * 2048 + t * 8 + k] > 0.5f) ? 1 : 0;
        cnt += loc[k];
    }
    part[t] = cnt;
    __syncthreads();
#pragma unroll
    for (int off = 1; off < 256; off <<= 1) {
        int v = (t >= off) ? part[t - off] : 0;
        __syncthreads();
        part[t] += v;
        __syncthreads();
    }
    const int total = part[255];
    if (t == 0) {
        hdr[b] = total;
        hdr[2 + b] = (total + 127) & ~127;
    }
    int base = part[t] - cnt;            // exclusive prefix
#pragma unroll
    for (int k = 0; k < 8; ++k)
        if (loc[k]) sidx[b * 2048 + (base++)] = t * 8 + k;
    for (int j = total + t; j < 2048; j += 256) sidx[b * 2048 + j] = -1;
}

// ---------------------------------------------------------------------------
// Prep (R7 form): gather X -> compact bf16 Xc; out-init for masked rows.
// ---------------------------------------------------------------------------
__global__ __launch_bounds__(256) void prep_kernel(
    const float* __restrict__ X, const float* __restrict__ mask,
    const float* __restrict__ bo, const int* __restrict__ sidx,
    const int* __restrict__ hdr,
    unsigned short* __restrict__ Xc, float* __restrict__ out)
{
    const int bx = blockIdx.x, t = threadIdx.x;
    if (bx < 4096) {
        const int b = bx >> 11, j = bx & 2047;
        if (j >= hdr[2 + b]) return;
        const int col = t * 4;
        bf16x4 o;
        if (j < hdr[b]) {
            int s = sidx[b * 2048 + j];
            f32x4 v = *(const f32x4*)&X[(size_t)(b * 2048 + s) * 1024 + col];
            o = (bf16x4){ (__bf16)v[0], (__bf16)v[1], (__bf16)v[2], (__bf16)v[3] };
        } else {
            o = (bf16x4){ (__bf16)0.f, (__bf16)0.f, (__bf16)0.f, (__bf16)0.f };
        }
        *(bf16x4*)&Xc[(size_t)bx * 1024 + col] = o;
    } else {
        int row = bx - 4096;
        int b = row >> 11, s = row & 2047;
        if (mask[b * 2048 + s] > 0.5f) return;   // oproj writes this row fully
        int e = t * 4;
        f32x4 v = *(const f32x4*)&bo[e];
        *(f32x4*)&out[(size_t)row * 1024 + e] = v;
    }
}

// ---------------------------------------------------------------------------
// Fused QKV projection (R7 form, best measured): 64x64 tiles, 32 KB dbuf,
// depth-2 counted-vmcnt staging from bf16 Xc, XCD swizzle. grid (64, 48).
// ---------------------------------------------------------------------------
__global__ __launch_bounds__(256, 5) void qkv_kernel(
    const unsigned short* __restrict__ Xc, const unsigned short* __restrict__ Wb,
    const float* __restrict__ bq, const float* __restrict__ bk,
    const float* __restrict__ bv, const int* __restrict__ hdr,
    unsigned short* __restrict__ Qc, unsigned short* __restrict__ Kc,
    unsigned short* __restrict__ VTc)
{
    __shared__ __align__(16) unsigned short SMEM[16384];   // 32 KB

    const int ln = blockIdx.y * 64 + blockIdx.x;   // 3072 blocks
    const int xcd = ln & 7, idx = ln >> 3;
    const int wy = xcd * 6 + idx % 6;               // 0..47
    const int wx = idx / 6;                         // 0..63

    const int m0 = wx * 64;
    const int b = m0 >> 11;
    if ((m0 & 2047) >= hdr[2 + b]) return;

    const int t = threadIdx.x;
    const int lane = t & 63, w = t >> 6;
    const int l15 = lane & 15, grp = lane >> 4;
    const int which = wy >> 4;                      // 0..2
    const int e0 = (wy & 15) * 64;

    const unsigned short* Wmat = Wb + which * 1048576;
    const float* bias = (which == 0) ? bq : (which == 1) ? bk : bv;

    const int srow = lane >> 3, sc_ = lane & 7;

    f32x4 acc[4];
#pragma unroll
    for (int i = 0; i < 4; ++i) acc[i] = (f32x4){0.f, 0.f, 0.f, 0.f};

    auto stage = [&](int p, int kt) {
        const int k0 = kt * 64;
        unsigned short* As = SMEM + p * 8192;
        unsigned short* Bs = As + 4096;
#pragma unroll
        for (int jj = 0; jj < 2; ++jj) {
            int inst = w * 2 + jj;
            int row = inst * 8 + srow;
            int cs = sc_ ^ (row & 7);
            ldsdma16(&As[inst * 512], &Xc[(m0 + row) * 1024 + k0 + cs * 8]);
        }
#pragma unroll
        for (int jj = 0; jj < 2; ++jj) {
            int inst = w * 2 + jj;
            int row = inst * 8 + srow;
            int cs = sc_ ^ (row & 7);
            ldsdma16(&Bs[inst * 512], &Wmat[(e0 + row) * 1024 + k0 + cs * 8]);
        }
    };

    stage(0, 0);
    stage(1, 1);
    int cur = 0;
    for (int kt = 0; kt < 16; ++kt) {
        if (kt < 14) asm volatile("s_waitcnt vmcnt(4)" ::: "memory");
        else         asm volatile("s_waitcnt vmcnt(0)" ::: "memory");
        __builtin_amdgcn_s_barrier();
        const unsigned short* As = SMEM + cur * 8192;
        const unsigned short* Bs = As + 4096;
#pragma unroll
        for (int kk = 0; kk < 64; kk += 32) {
            const int cb = kk >> 3;
            bf16x8 af[4], bfr;
#pragma unroll
            for (int i = 0; i < 4; ++i) {
                int r = i * 16 + l15;
                af[i] = ld8(&As[r * 64 + (((cb + grp) ^ (r & 7)) << 3)]);
            }
            {
                int r = w * 16 + l15;
                bfr = ld8(&Bs[r * 64 + (((cb + grp) ^ (r & 7)) << 3)]);
            }
            __builtin_amdgcn_s_setprio(1);
#pragma unroll
            for (int i = 0; i < 4; ++i)
                acc[i] = __builtin_amdgcn_mfma_f32_16x16x32_bf16(
                    af[i], bfr, acc[i], 0, 0, 0);
            __builtin_amdgcn_s_setprio(0);
        }
        __builtin_amdgcn_s_barrier();
        if (kt + 2 < 16) stage(cur, kt + 2);
        cur ^= 1;
    }

    const int h = e0 >> 6;                 // single head per 64-slice
    if (which == 2) {
        // stage transposed into SMEM[col][row], stride 72 (pad 8)
        {
            int e = e0 + w * 16 + l15;
            float bv_ = bias[e];
#pragma unroll
            for (int i = 0; i < 4; ++i) {
                u16x4 pk;
#pragma unroll
                for (int r = 0; r < 4; ++r) pk[r] = f2bf_n(acc[i][r] + bv_);
                *(u16x4*)&SMEM[(w * 16 + l15) * 72 + i * 16 + grp * 4] = pk;
            }
        }
        __syncthreads();
        const int s0 = m0 & 2047;
#pragma unroll
        for (int round = 0; round < 2; ++round) {
            int dhl = (t >> 3) + round * 32;   // 0..63 (dh)
            int chunk = t & 7;                 // s chunk
            *(short8*)&VTc[((b * 16 + h) * 64 + dhl) * 2048 + s0 + chunk * 8] =
                *(const short8*)&SMEM[dhl * 72 + chunk * 8];
        }
    } else {
        const float scale = (which == 0) ? 0.125f : 1.0f;
        {
            int e = e0 + w * 16 + l15;
            float bv_ = bias[e];
#pragma unroll
            for (int i = 0; i < 4; ++i)
#pragma unroll
                for (int r = 0; r < 4; ++r)
                    SMEM[(i * 16 + grp * 4 + r) * 72 + w * 16 + l15] =
                        f2bf_n((acc[i][r] + bv_) * scale);
        }
        __syncthreads();
        unsigned short* dst = (which == 0) ? Qc : Kc;
#pragma unroll
        for (int round = 0; round < 2; ++round) {
            int tl = (t >> 3) + round * 32;    // row (s offset)
            int chunk = t & 7;                 // dh chunk
            int s = (m0 & 2047) + tl;
            *(short8*)&dst[((b * 16 + h) * 2048 + s) * 64 + chunk * 8] =
                *(const short8*)&SMEM[tl * 72 + chunk * 8];
        }
    }
}

// ---------------------------------------------------------------------------
// Flash attention v12: QBLK=64 with 4-way split-K (8 waves = 4 khalf x 2 qg)
// -> 512 active blocks = 2 blocks/CU (vs 1 before): a second co-resident
// block hides staging/barrier stalls. Per-wave: 32 keys (rK=khalf*32+l31),
// no g-loop; staging/vmcnt/barrier structure identical to v8. 4-way merge
// through LDS scratch (2 qg x 3 src x 2080 f32 = 50 KB, after final barrier).
// XCD co-location: ln = (hi:2)(qb:5)(xcd:3). grid (32, 32), 512 thr.
// ---------------------------------------------------------------------------
__global__ __launch_bounds__(512, 4) void attn_kernel(
    const unsigned short* __restrict__ Qc, const unsigned short* __restrict__ Kc,
    const unsigned short* __restrict__ VTc, const int* __restrict__ hdr,
    unsigned short* __restrict__ Xattn)
{
    __shared__ __align__(16) unsigned short SMEM[32768];   // 64 KB
    float* mrg = (float*)SMEM;

    const int ln = blockIdx.y * 32 + blockIdx.x;   // 1024 blocks
    const int qb = (ln >> 3) & 31;
    const int bh = ((ln >> 8) << 3) | (ln & 7);
    const int b = bh >> 4;
    const int nbl = hdr[b], nbpl = hdr[2 + b];
    const int q0 = qb * 64;
    if (q0 >= nbpl) return;

    const int t = threadIdx.x;
    const int lane = t & 63, w = t >> 6;
    const int l31 = lane & 31, half = lane >> 5;
    const int qg = w & 1, khalf = w >> 1;          // khalf in [0,4)

    const unsigned short* Kp = Kc + (size_t)bh * 131072;
    const unsigned short* Vp = VTc + (size_t)bh * 131072;

    bf16x8 qf[4];
#pragma unroll
    for (int s = 0; s < 4; ++s)
        qf[s] = ld8(&Qc[(bh * 2048 + q0 + qg * 32 + l31) * 64 + s * 16 + half * 8]);

    f32x16 accd[2];
    float lsum = 0.f;
#pragma unroll
    for (int d = 0; d < 2; ++d)
#pragma unroll
        for (int r = 0; r < 16; ++r) accd[d][r] = 0.f;

    auto stageKV = [&](int p, int kb) {
        const int k0 = kb * 128;
        unsigned short* Ks = SMEM + p * 16384;
        unsigned short* Vs = Ks + 8192;
#pragma unroll
        for (int ii = 0; ii < 2; ++ii) {
            int inst = w * 2 + ii;
            int row = inst * 8 + (lane >> 3);
            int cs = (lane & 7) ^ (row & 7);
            ldsdma16(&Ks[inst * 512], &Kp[(k0 + row) * 64 + cs * 8]);
        }
#pragma unroll
        for (int ii = 0; ii < 2; ++ii) {
            int inst = w * 2 + ii;
            int row = inst * 4 + (lane >> 4);
            int cs = (lane & 15) ^ (row & 15);
            ldsdma16(&Vs[inst * 512], &Vp[row * 2048 + k0 + cs * 8]);
        }
    };

    const int nkb = nbpl >> 7;
    stageKV(0, 0);
    if (nkb > 1) stageKV(1, 1);
    int cur = 0;
    for (int kb = 0; kb < nkb; ++kb) {
        const int k0 = kb * 128;
        if (kb < nkb - 2) asm volatile("s_waitcnt vmcnt(4)" ::: "memory");
        else              asm volatile("s_waitcnt vmcnt(0)" ::: "memory");
        __builtin_amdgcn_s_barrier();
        const unsigned short* Ks = SMEM + cur * 16384;
        const unsigned short* Vs = Ks + 8192;

        f32x16 z;
#pragma unroll
        for (int r = 0; r < 16; ++r) z[r] = 0.f;
        const int rK = khalf * 32 + l31;
        __builtin_amdgcn_s_setprio(1);
#pragma unroll
        for (int s = 0; s < 4; ++s) {
            int chunk = s * 2 + half;
            bf16x8 kf = ld8(&Ks[rK * 64 + ((chunk ^ (rK & 7)) << 3)]);
            // SWAPPED operands: A=K rows (key=l31), B=Q cols (q=l31)
            z = __builtin_amdgcn_mfma_f32_32x32x16_bf16(kf, qf[s], z, 0, 0, 0);
        }
        __builtin_amdgcn_s_setprio(0);
        // masked softmax numerator; key(r) = (r&3)+8*(r>>2)+4*half
        const int rem = nbl - (k0 + khalf * 32);
#pragma unroll
        for (int r = 0; r < 16; ++r) z[r] = __expf(z[r]);
        if (rem < 32) {
#pragma unroll
            for (int r = 0; r < 16; ++r) {
                int kr = (r & 3) + 8 * (r >> 2) + 4 * half;
                if (kr >= rem) z[r] = 0.f;
            }
        }
#pragma unroll
        for (int r = 0; r < 16; ++r) lsum += z[r];

        unsigned int wd[8];
#pragma unroll
        for (int j = 0; j < 8; ++j)
            asm("v_cvt_pk_bf16_f32 %0, %1, %2"
                : "=v"(wd[j]) : "v"(z[2 * j]), "v"(z[2 * j + 1]));
        {
            u32x2 r0 = __builtin_amdgcn_permlane32_swap(wd[0], wd[2], false, false);
            wd[0] = r0[0]; wd[2] = r0[1];
            u32x2 r1 = __builtin_amdgcn_permlane32_swap(wd[1], wd[3], false, false);
            wd[1] = r1[0]; wd[3] = r1[1];
            u32x2 r2 = __builtin_amdgcn_permlane32_swap(wd[4], wd[6], false, false);
            wd[4] = r2[0]; wd[6] = r2[1];
            u32x2 r3 = __builtin_amdgcn_permlane32_swap(wd[5], wd[7], false, false);
            wd[5] = r3[0]; wd[7] = r3[1];
        }
        bf16x8 pf[2];
        pf[0] = __builtin_bit_cast(bf16x8, (u32x4){wd[0], wd[1], wd[2], wd[3]});
        pf[1] = __builtin_bit_cast(bf16x8, (u32x4){wd[4], wd[5], wd[6], wd[7]});

        __builtin_amdgcn_s_setprio(1);
#pragma unroll
        for (int d = 0; d < 2; ++d) {
            const int rV = d * 32 + l31;
#pragma unroll
            for (int sp = 0; sp < 2; ++sp) {
                int chunk = khalf * 4 + sp * 2 + half;
                bf16x8 vf = ld8(&Vs[rV * 128 + ((chunk ^ (rV & 15)) << 3)]);
                accd[d] = __builtin_amdgcn_mfma_f32_32x32x16_bf16(
                    pf[sp], vf, accd[d], 0, 0, 0);
            }
        }
        __builtin_amdgcn_s_setprio(0);

        __builtin_amdgcn_s_barrier();
        if (kb + 2 < nkb) stageKV(cur, kb + 2);
        cur ^= 1;
    }

    // merge lane halves of the denominator: all lanes hold sum for q=l31
    lsum += __shfl_xor(lsum, 32, 64);

    // 4-way split-K merge: khalf 1..3 write, khalf 0 reduces.
    float* q_ = mrg + qg * 6240;                   // 3 x 2080 per qg
    if (khalf != 0) {
        float* dst = q_ + (khalf - 1) * 2080;
#pragma unroll
        for (int r = 0; r < 16; ++r) {
            dst[(r) * 64 + lane]      = accd[0][r];
            dst[(16 + r) * 64 + lane] = accd[1][r];
        }
        if (half == 0) dst[2048 + l31] = lsum;
    }
    __syncthreads();
    if (khalf == 0) {
        float tot = lsum;
#pragma unroll
        for (int src = 0; src < 3; ++src) {
            const float* sp_ = q_ + src * 2080;
#pragma unroll
            for (int r = 0; r < 16; ++r) {
                accd[0][r] += sp_[(r) * 64 + lane];
                accd[1][r] += sp_[(16 + r) * 64 + lane];
            }
            tot += sp_[2048 + l31];
        }
#pragma unroll
        for (int r = 0; r < 16; ++r) {
            int ql = (r & 3) + 8 * (r >> 2) + 4 * half;
            int j = q0 + qg * 32 + ql;
            float lr = __shfl(tot, ql, 64);  // lane ql holds q=ql's sum
            float inv = 1.f / (lr + 1e-13f);
#pragma unroll
            for (int d = 0; d < 2; ++d)
                Xattn[(b * 2048 + j) * 1024 + (bh & 15) * 64 + d * 32 + l31] =
                    f2bf_n(accd[d][r] * inv);
        }
    }
}

// ---------------------------------------------------------------------------
// Output projection (R7 form): 64x64 core, 32 KB dbuf, vmcnt(4) depth-2.
// grid (64, 16), 256 thr.
// ---------------------------------------------------------------------------
__global__ __launch_bounds__(256, 5) void oproj_kernel(
    const unsigned short* __restrict__ A, const unsigned short* __restrict__ W,
    const float* __restrict__ bias, const int* __restrict__ sidx,
    const int* __restrict__ hdr, float* __restrict__ out)
{
    __shared__ __align__(16) unsigned short SMEM[16384];   // 32 KB

    const int ln = blockIdx.y * 64 + blockIdx.x;   // 1024 blocks
    const int xcd = ln & 7, idx = ln >> 3;
    const int wy = xcd * 2 + (idx & 1);             // 0..15
    const int wx = idx >> 1;                        // 0..63

    const int m0 = wx * 64;
    const int b = m0 >> 11;
    const int nbl = hdr[b];
    if ((m0 & 2047) >= hdr[2 + b]) return;

    const int t = threadIdx.x;
    const int lane = t & 63, w = t >> 6;
    const int l15 = lane & 15, grp = lane >> 4;
    const int e0 = wy * 64;
    const int srow = lane >> 3, sc_ = lane & 7;

    f32x4 acc[4];
#pragma unroll
    for (int i = 0; i < 4; ++i) acc[i] = (f32x4){0.f, 0.f, 0.f, 0.f};

    auto stage = [&](int p, int kt) {
        const int k0 = kt * 64;
        unsigned short* As = SMEM + p * 8192;
        unsigned short* Bs = As + 4096;
#pragma unroll
        for (int jj = 0; jj < 2; ++jj) {
            int inst = w * 2 + jj;
            int row = inst * 8 + srow;
            int cs = sc_ ^ (row & 7);
            ldsdma16(&As[inst * 512], &A[(m0 + row) * 1024 + k0 + cs * 8]);
        }
#pragma unroll
        for (int jj = 0; jj < 2; ++jj) {
            int inst = w * 2 + jj;
            int row = inst * 8 + srow;
            int cs = sc_ ^ (row & 7);
            ldsdma16(&Bs[inst * 512], &W[(e0 + row) * 1024 + k0 + cs * 8]);
        }
    };

    stage(0, 0);
    stage(1, 1);
    int cur = 0;
    for (int kt = 0; kt < 16; ++kt) {
        if (kt < 14) asm volatile("s_waitcnt vmcnt(4)" ::: "memory");
        else         asm volatile("s_waitcnt vmcnt(0)" ::: "memory");
        __builtin_amdgcn_s_barrier();
        const unsigned short* As = SMEM + cur * 8192;
        const unsigned short* Bs = As + 4096;
#pragma unroll
        for (int kk = 0; kk < 64; kk += 32) {
            const int cb = kk >> 3;
            bf16x8 af[4], bfr;
#pragma unroll
            for (int i = 0; i < 4; ++i) {
                int r = i * 16 + l15;
                af[i] = ld8(&As[r * 64 + (((cb + grp) ^ (r & 7)) << 3)]);
            }
            {
                int r = w * 16 + l15;
                bfr = ld8(&Bs[r * 64 + (((cb + grp) ^ (r & 7)) << 3)]);
            }
            __builtin_amdgcn_s_setprio(1);
#pragma unroll
            for (int i = 0; i < 4; ++i)
                acc[i] = __builtin_amdgcn_mfma_f32_16x16x32_bf16(
                    af[i], bfr, acc[i], 0, 0, 0);
            __builtin_amdgcn_s_setprio(0);
        }
        __builtin_amdgcn_s_barrier();
        if (kt + 2 < 16) stage(cur, kt + 2);
        cur ^= 1;
    }

    {
        int e = e0 + w * 16 + l15;
        float bv_ = bias[e];
#pragma unroll
        for (int i = 0; i < 4; ++i)
#pragma unroll
            for (int r = 0; r < 4; ++r) {
                int jl = (m0 & 2047) + i * 16 + grp * 4 + r;
                if (jl < nbl) {
                    int s = sidx[b * 2048 + jl];
                    out[(size_t)(b * 2048 + s) * 1024 + e] = acc[i][r] + bv_;
                }
            }
    }
}

extern "C" void kernel_launch(void* const* d_in, const int* in_sizes, int n_in,
                              void* d_out, int out_size, void* d_ws, size_t ws_size,
                              hipStream_t stream) {
    const float* x    = (const float*)d_in[0];
    const float* mask = (const float*)d_in[1];
    const float* Wq   = (const float*)d_in[2];
    const float* bq   = (const float*)d_in[3];
    const float* Wk   = (const float*)d_in[4];
    const float* bk   = (const float*)d_in[5];
    const float* Wv   = (const float*)d_in[6];
    const float* bv   = (const float*)d_in[7];
    const float* Wo   = (const float*)d_in[8];
    const float* bo   = (const float*)d_in[9];
    float* out = (float*)d_out;

    unsigned short* Qc   = (unsigned short*)d_ws;    // u16 element offsets:
    unsigned short* Kc   = Qc + 4194304;
    unsigned short* VTc  = Qc + 8388608;
    unsigned short* XcXa = Qc + 12582912;            // Xc (prep->qkv), then Xattn
    unsigned short* Wb   = Qc + 16777216;
    int* sidx            = (int*)(Qc + 20971520);    // 4096 ints
    int* hdr             = sidx + 4096;              // nb[2], nbp[2]

    compact_kernel<<<dim3(4098), 256, 0, stream>>>(mask, Wq, Wk, Wv, Wo,
                                                   sidx, hdr, Wb);
    prep_kernel<<<dim3(8192), 256, 0, stream>>>(x, mask, bo, sidx, hdr,
                                                XcXa, out);
    qkv_kernel<<<dim3(64, 48), 256, 0, stream>>>(XcXa, Wb, bq, bk, bv, hdr,
                                                 Qc, Kc, VTc);
    attn_kernel<<<dim3(32, 32), 512, 0, stream>>>(Qc, Kc, VTc, hdr, XcXa);
    oproj_kernel<<<dim3(64, 16), 256, 0, stream>>>(XcXa, Wb + 3145728, bo,
                                                   sidx, hdr, out);
}

// Round 12
// 159.469 us; speedup vs baseline: 1.0824x; 1.0232x over previous
//
#include <hip/hip_runtime.h>
#include <stdint.h>

#define DEV __device__ __forceinline__

typedef __attribute__((ext_vector_type(4))) float f32x4;
typedef __attribute__((ext_vector_type(16))) float f32x16;
typedef __attribute__((ext_vector_type(8))) __bf16 bf16x8;
typedef __attribute__((ext_vector_type(4))) __bf16 bf16x4;
typedef __attribute__((ext_vector_type(8))) short short8;
typedef __attribute__((ext_vector_type(4))) unsigned short u16x4;
typedef __attribute__((ext_vector_type(2))) unsigned int u32x2;
typedef __attribute__((ext_vector_type(4))) unsigned int u32x4;

DEV unsigned short f2bf_n(float f) {
    __bf16 h = (__bf16)f;
    return __builtin_bit_cast(unsigned short, h);
}
DEV bf16x8 ld8(const unsigned short* p) {
    short8 v = *(const short8*)p;
    return __builtin_bit_cast(bf16x8, v);
}
DEV void ldsdma16(unsigned short* lds, const unsigned short* g) {
    __builtin_amdgcn_global_load_lds(
        (const __attribute__((address_space(1))) unsigned int*)g,
        (__attribute__((address_space(3))) unsigned int*)lds, 16, 0, 0);
}

// ---------------------------------------------------------------------------
// Fused compact + W-convert (R7 form). Blocks 0-1: scan; 2..4097: W->bf16.
// ---------------------------------------------------------------------------
__global__ __launch_bounds__(256) void compact_kernel(
    const float* __restrict__ mask,
    const float* __restrict__ Wq, const float* __restrict__ Wk,
    const float* __restrict__ Wv, const float* __restrict__ Wo,
    int* __restrict__ sidx, int* __restrict__ hdr,
    unsigned short* __restrict__ Wb)
{
    const int t = threadIdx.x;
    if (blockIdx.x >= 2) {
        int c = (blockIdx.x - 2) * 256 + t;
        int wsel = c >> 18, off = (c & 262143) * 4;
        const float* ws_[4] = { Wq, Wk, Wv, Wo };
        f32x4 v = *(const f32x4*)(ws_[wsel] + off);
        bf16x4 b = { (__bf16)v[0], (__bf16)v[1], (__bf16)v[2], (__bf16)v[3] };
        *(bf16x4*)&Wb[wsel * 1048576 + off] = b;
        return;
    }
    __shared__ int part[256];
    const int b = blockIdx.x;
    int loc[8], cnt = 0;
#pragma unroll
    for (int k = 0; k < 8; ++k) {
        loc[k] = (mask[b * 2048 + t * 8 + k] > 0.5f) ? 1 : 0;
        cnt += loc[k];
    }
    part[t] = cnt;
    __syncthreads();
#pragma unroll
    for (int off = 1; off < 256; off <<= 1) {
        int v = (t >= off) ? part[t - off] : 0;
        __syncthreads();
        part[t] += v;
        __syncthreads();
    }
    const int total = part[255];
    if (t == 0) {
        hdr[b] = total;
        hdr[2 + b] = (total + 127) & ~127;
    }
    int base = part[t] - cnt;            // exclusive prefix
#pragma unroll
    for (int k = 0; k < 8; ++k)
        if (loc[k]) sidx[b * 2048 + (base++)] = t * 8 + k;
    for (int j = total + t; j < 2048; j += 256) sidx[b * 2048 + j] = -1;
}

// ---------------------------------------------------------------------------
// Prep v13: gather ONLY (out-init moved to the oproj launch, off qkv's
// critical path). grid 4096 x 256 thr.
// ---------------------------------------------------------------------------
__global__ __launch_bounds__(256) void prep_kernel(
    const float* __restrict__ X, const int* __restrict__ sidx,
    const int* __restrict__ hdr, unsigned short* __restrict__ Xc)
{
    const int bx = blockIdx.x, t = threadIdx.x;
    const int b = bx >> 11, j = bx & 2047;
    if (j >= hdr[2 + b]) return;
    const int col = t * 4;
    bf16x4 o;
    if (j < hdr[b]) {
        int s = sidx[b * 2048 + j];
        f32x4 v = *(const f32x4*)&X[(size_t)(b * 2048 + s) * 1024 + col];
        o = (bf16x4){ (__bf16)v[0], (__bf16)v[1], (__bf16)v[2], (__bf16)v[3] };
    } else {
        o = (bf16x4){ (__bf16)0.f, (__bf16)0.f, (__bf16)0.f, (__bf16)0.f };
    }
    *(bf16x4*)&Xc[(size_t)bx * 1024 + col] = o;
}

// ---------------------------------------------------------------------------
// Fused QKV projection (R7 form, best measured): 64x64 tiles, 32 KB dbuf,
// depth-2 counted-vmcnt staging from bf16 Xc, XCD swizzle. grid (64, 48).
// ---------------------------------------------------------------------------
__global__ __launch_bounds__(256, 5) void qkv_kernel(
    const unsigned short* __restrict__ Xc, const unsigned short* __restrict__ Wb,
    const float* __restrict__ bq, const float* __restrict__ bk,
    const float* __restrict__ bv, const int* __restrict__ hdr,
    unsigned short* __restrict__ Qc, unsigned short* __restrict__ Kc,
    unsigned short* __restrict__ VTc)
{
    __shared__ __align__(16) unsigned short SMEM[16384];   // 32 KB

    const int ln = blockIdx.y * 64 + blockIdx.x;   // 3072 blocks
    const int xcd = ln & 7, idx = ln >> 3;
    const int wy = xcd * 6 + idx % 6;               // 0..47
    const int wx = idx / 6;                         // 0..63

    const int m0 = wx * 64;
    const int b = m0 >> 11;
    if ((m0 & 2047) >= hdr[2 + b]) return;

    const int t = threadIdx.x;
    const int lane = t & 63, w = t >> 6;
    const int l15 = lane & 15, grp = lane >> 4;
    const int which = wy >> 4;                      // 0..2
    const int e0 = (wy & 15) * 64;

    const unsigned short* Wmat = Wb + which * 1048576;
    const float* bias = (which == 0) ? bq : (which == 1) ? bk : bv;

    const int srow = lane >> 3, sc_ = lane & 7;

    f32x4 acc[4];
#pragma unroll
    for (int i = 0; i < 4; ++i) acc[i] = (f32x4){0.f, 0.f, 0.f, 0.f};

    auto stage = [&](int p, int kt) {
        const int k0 = kt * 64;
        unsigned short* As = SMEM + p * 8192;
        unsigned short* Bs = As + 4096;
#pragma unroll
        for (int jj = 0; jj < 2; ++jj) {
            int inst = w * 2 + jj;
            int row = inst * 8 + srow;
            int cs = sc_ ^ (row & 7);
            ldsdma16(&As[inst * 512], &Xc[(m0 + row) * 1024 + k0 + cs * 8]);
        }
#pragma unroll
        for (int jj = 0; jj < 2; ++jj) {
            int inst = w * 2 + jj;
            int row = inst * 8 + srow;
            int cs = sc_ ^ (row & 7);
            ldsdma16(&Bs[inst * 512], &Wmat[(e0 + row) * 1024 + k0 + cs * 8]);
        }
    };

    stage(0, 0);
    stage(1, 1);
    int cur = 0;
    for (int kt = 0; kt < 16; ++kt) {
        if (kt < 14) asm volatile("s_waitcnt vmcnt(4)" ::: "memory");
        else         asm volatile("s_waitcnt vmcnt(0)" ::: "memory");
        __builtin_amdgcn_s_barrier();
        const unsigned short* As = SMEM + cur * 8192;
        const unsigned short* Bs = As + 4096;
#pragma unroll
        for (int kk = 0; kk < 64; kk += 32) {
            const int cb = kk >> 3;
            bf16x8 af[4], bfr;
#pragma unroll
            for (int i = 0; i < 4; ++i) {
                int r = i * 16 + l15;
                af[i] = ld8(&As[r * 64 + (((cb + grp) ^ (r & 7)) << 3)]);
            }
            {
                int r = w * 16 + l15;
                bfr = ld8(&Bs[r * 64 + (((cb + grp) ^ (r & 7)) << 3)]);
            }
            __builtin_amdgcn_s_setprio(1);
#pragma unroll
            for (int i = 0; i < 4; ++i)
                acc[i] = __builtin_amdgcn_mfma_f32_16x16x32_bf16(
                    af[i], bfr, acc[i], 0, 0, 0);
            __builtin_amdgcn_s_setprio(0);
        }
        __builtin_amdgcn_s_barrier();
        if (kt + 2 < 16) stage(cur, kt + 2);
        cur ^= 1;
    }

    const int h = e0 >> 6;                 // single head per 64-slice
    if (which == 2) {
        // stage transposed into SMEM[col][row], stride 72 (pad 8)
        {
            int e = e0 + w * 16 + l15;
            float bv_ = bias[e];
#pragma unroll
            for (int i = 0; i < 4; ++i) {
                u16x4 pk;
#pragma unroll
                for (int r = 0; r < 4; ++r) pk[r] = f2bf_n(acc[i][r] + bv_);
                *(u16x4*)&SMEM[(w * 16 + l15) * 72 + i * 16 + grp * 4] = pk;
            }
        }
        __syncthreads();
        const int s0 = m0 & 2047;
#pragma unroll
        for (int round = 0; round < 2; ++round) {
            int dhl = (t >> 3) + round * 32;   // 0..63 (dh)
            int chunk = t & 7;                 // s chunk
            *(short8*)&VTc[((b * 16 + h) * 64 + dhl) * 2048 + s0 + chunk * 8] =
                *(const short8*)&SMEM[dhl * 72 + chunk * 8];
        }
    } else {
        const float scale = (which == 0) ? 0.125f : 1.0f;
        {
            int e = e0 + w * 16 + l15;
            float bv_ = bias[e];
#pragma unroll
            for (int i = 0; i < 4; ++i)
#pragma unroll
                for (int r = 0; r < 4; ++r)
                    SMEM[(i * 16 + grp * 4 + r) * 72 + w * 16 + l15] =
                        f2bf_n((acc[i][r] + bv_) * scale);
        }
        __syncthreads();
        unsigned short* dst = (which == 0) ? Qc : Kc;
#pragma unroll
        for (int round = 0; round < 2; ++round) {
            int tl = (t >> 3) + round * 32;    // row (s offset)
            int chunk = t & 7;                 // dh chunk
            int s = (m0 & 2047) + tl;
            *(short8*)&dst[((b * 16 + h) * 2048 + s) * 64 + chunk * 8] =
                *(const short8*)&SMEM[tl * 72 + chunk * 8];
        }
    }
}

// ---------------------------------------------------------------------------
// Flash attention (R7/v8 form, best measured): QBLK=128, 2-way split-K,
// staged K/V depth-2 counted-vmcnt, in-register softmax, XCD co-location.
// grid (16, 32), 512 thr. LDS 64 KB.
// ---------------------------------------------------------------------------
__global__ __launch_bounds__(512, 4) void attn_kernel(
    const unsigned short* __restrict__ Qc, const unsigned short* __restrict__ Kc,
    const unsigned short* __restrict__ VTc, const int* __restrict__ hdr,
    unsigned short* __restrict__ Xattn)
{
    __shared__ __align__(16) unsigned short SMEM[32768];   // 64 KB
    float* mrg = (float*)SMEM;

    // XCD co-location: all 16 q-blocks of head bh share ln&7 -> same XCD.
    const int ln = blockIdx.y * 16 + blockIdx.x;
    const int qb = (ln >> 3) & 15;
    const int bh = ((ln >> 7) << 3) | (ln & 7);
    const int b = bh >> 4;
    const int nbl = hdr[b], nbpl = hdr[2 + b];
    const int q0 = qb * 128;
    if (q0 >= nbpl) return;

    const int t = threadIdx.x;
    const int lane = t & 63, w = t >> 6;
    const int l31 = lane & 31, half = lane >> 5;
    const int qg = w & 3, khalf = w >> 2;

    const unsigned short* Kp = Kc + (size_t)bh * 131072;
    const unsigned short* Vp = VTc + (size_t)bh * 131072;

    bf16x8 qf[4];
#pragma unroll
    for (int s = 0; s < 4; ++s)
        qf[s] = ld8(&Qc[(bh * 2048 + q0 + qg * 32 + l31) * 64 + s * 16 + half * 8]);

    f32x16 accd[2];
    float lsum = 0.f;
#pragma unroll
    for (int d = 0; d < 2; ++d)
#pragma unroll
        for (int r = 0; r < 16; ++r) accd[d][r] = 0.f;

    auto stageKV = [&](int p, int kb) {
        const int k0 = kb * 128;
        unsigned short* Ks = SMEM + p * 16384;
        unsigned short* Vs = Ks + 8192;
#pragma unroll
        for (int ii = 0; ii < 2; ++ii) {
            int inst = w * 2 + ii;
            int row = inst * 8 + (lane >> 3);
            int cs = (lane & 7) ^ (row & 7);
            ldsdma16(&Ks[inst * 512], &Kp[(k0 + row) * 64 + cs * 8]);
        }
#pragma unroll
        for (int ii = 0; ii < 2; ++ii) {
            int inst = w * 2 + ii;
            int row = inst * 4 + (lane >> 4);
            int cs = (lane & 15) ^ (row & 15);
            ldsdma16(&Vs[inst * 512], &Vp[row * 2048 + k0 + cs * 8]);
        }
    };

    const int nkb = nbpl >> 7;
    stageKV(0, 0);
    if (nkb > 1) stageKV(1, 1);
    int cur = 0;
    for (int kb = 0; kb < nkb; ++kb) {
        const int k0 = kb * 128;
        if (kb < nkb - 2) asm volatile("s_waitcnt vmcnt(4)" ::: "memory");
        else              asm volatile("s_waitcnt vmcnt(0)" ::: "memory");
        __builtin_amdgcn_s_barrier();
        const unsigned short* Ks = SMEM + cur * 16384;
        const unsigned short* Vs = Ks + 8192;

#pragma unroll
        for (int g = 0; g < 2; ++g) {
            f32x16 z;
#pragma unroll
            for (int r = 0; r < 16; ++r) z[r] = 0.f;
            int rK = khalf * 64 + g * 32 + l31;
            __builtin_amdgcn_s_setprio(1);
#pragma unroll
            for (int s = 0; s < 4; ++s) {
                int chunk = s * 2 + half;
                bf16x8 kf = ld8(&Ks[rK * 64 + ((chunk ^ (rK & 7)) << 3)]);
                z = __builtin_amdgcn_mfma_f32_32x32x16_bf16(kf, qf[s], z, 0, 0, 0);
            }
            __builtin_amdgcn_s_setprio(0);
            const int rem = nbl - (k0 + khalf * 64 + g * 32);
#pragma unroll
            for (int r = 0; r < 16; ++r) z[r] = __expf(z[r]);
            if (rem < 32) {
#pragma unroll
                for (int r = 0; r < 16; ++r) {
                    int kr = (r & 3) + 8 * (r >> 2) + 4 * half;
                    if (kr >= rem) z[r] = 0.f;
                }
            }
#pragma unroll
            for (int r = 0; r < 16; ++r) lsum += z[r];

            unsigned int wd[8];
#pragma unroll
            for (int j = 0; j < 8; ++j)
                asm("v_cvt_pk_bf16_f32 %0, %1, %2"
                    : "=v"(wd[j]) : "v"(z[2 * j]), "v"(z[2 * j + 1]));
            {
                u32x2 r0 = __builtin_amdgcn_permlane32_swap(wd[0], wd[2], false, false);
                wd[0] = r0[0]; wd[2] = r0[1];
                u32x2 r1 = __builtin_amdgcn_permlane32_swap(wd[1], wd[3], false, false);
                wd[1] = r1[0]; wd[3] = r1[1];
                u32x2 r2 = __builtin_amdgcn_permlane32_swap(wd[4], wd[6], false, false);
                wd[4] = r2[0]; wd[6] = r2[1];
                u32x2 r3 = __builtin_amdgcn_permlane32_swap(wd[5], wd[7], false, false);
                wd[5] = r3[0]; wd[7] = r3[1];
            }
            bf16x8 pf[2];
            pf[0] = __builtin_bit_cast(bf16x8, (u32x4){wd[0], wd[1], wd[2], wd[3]});
            pf[1] = __builtin_bit_cast(bf16x8, (u32x4){wd[4], wd[5], wd[6], wd[7]});

            __builtin_amdgcn_s_setprio(1);
#pragma unroll
            for (int d = 0; d < 2; ++d) {
                int rV = d * 32 + l31;
#pragma unroll
                for (int sp = 0; sp < 2; ++sp) {
                    int chunk = khalf * 8 + g * 4 + sp * 2 + half;
                    bf16x8 vf = ld8(&Vs[rV * 128 + ((chunk ^ (rV & 15)) << 3)]);
                    accd[d] = __builtin_amdgcn_mfma_f32_32x32x16_bf16(
                        pf[sp], vf, accd[d], 0, 0, 0);
                }
            }
            __builtin_amdgcn_s_setprio(0);
        }
        __builtin_amdgcn_s_barrier();
        if (kb + 2 < nkb) stageKV(cur, kb + 2);
        cur ^= 1;
    }

    lsum += __shfl_xor(lsum, 32, 64);

    float* q_ = mrg + qg * 2080;
    if (khalf == 1) {
#pragma unroll
        for (int r = 0; r < 16; ++r) {
            q_[(r) * 64 + lane]      = accd[0][r];
            q_[(16 + r) * 64 + lane] = accd[1][r];
        }
        if (half == 0) q_[2048 + l31] = lsum;
    }
    __syncthreads();
    if (khalf == 0) {
#pragma unroll
        for (int r = 0; r < 16; ++r) {
            accd[0][r] += q_[(r) * 64 + lane];
            accd[1][r] += q_[(16 + r) * 64 + lane];
        }
        float tot = lsum + q_[2048 + l31];
#pragma unroll
        for (int r = 0; r < 16; ++r) {
            int ql = (r & 3) + 8 * (r >> 2) + 4 * half;
            int j = q0 + qg * 32 + ql;
            float lr = __shfl(tot, ql, 64);
            float inv = 1.f / (lr + 1e-13f);
#pragma unroll
            for (int d = 0; d < 2; ++d)
                Xattn[(b * 2048 + j) * 1024 + (bh & 15) * 64 + d * 32 + l31] =
                    f2bf_n(accd[d][r] * inv);
        }
    }
}

// ---------------------------------------------------------------------------
// Output projection v13: R7 64x64 GEMM core + appended out-init blocks
// (1024..5119) that write bo into MASKED rows. Disjoint rows from the GEMM
// scatter (which writes unmasked rows only) -> no race; init blocks exit
// before any barrier. Rides on oproj's idle CUs instead of serializing in
// prep. 1D grid 5120, 256 thr.
// ---------------------------------------------------------------------------
__global__ __launch_bounds__(256, 5) void oproj_kernel(
    const unsigned short* __restrict__ A, const unsigned short* __restrict__ W,
    const float* __restrict__ bias, const int* __restrict__ sidx,
    const int* __restrict__ hdr, const float* __restrict__ mask,
    float* __restrict__ out)
{
    __shared__ __align__(16) unsigned short SMEM[16384];   // 32 KB

    if (blockIdx.x >= 1024) {
        int row = blockIdx.x - 1024;                // 0..4095
        int b = row >> 11, s = row & 2047;
        if (mask[b * 2048 + s] > 0.5f) return;      // GEMM writes this row
        int e = threadIdx.x * 4;
        f32x4 v = *(const f32x4*)&bias[e];          // bias == bo
        *(f32x4*)&out[(size_t)row * 1024 + e] = v;
        return;
    }

    const int ln = blockIdx.x;                      // 0..1023
    const int xcd = ln & 7, idx = ln >> 3;
    const int wy = xcd * 2 + (idx & 1);             // 0..15
    const int wx = idx >> 1;                        // 0..63

    const int m0 = wx * 64;
    const int b = m0 >> 11;
    const int nbl = hdr[b];
    if ((m0 & 2047) >= hdr[2 + b]) return;

    const int t = threadIdx.x;
    const int lane = t & 63, w = t >> 6;
    const int l15 = lane & 15, grp = lane >> 4;
    const int e0 = wy * 64;
    const int srow = lane >> 3, sc_ = lane & 7;

    f32x4 acc[4];
#pragma unroll
    for (int i = 0; i < 4; ++i) acc[i] = (f32x4){0.f, 0.f, 0.f, 0.f};

    auto stage = [&](int p, int kt) {
        const int k0 = kt * 64;
        unsigned short* As = SMEM + p * 8192;
        unsigned short* Bs = As + 4096;
#pragma unroll
        for (int jj = 0; jj < 2; ++jj) {
            int inst = w * 2 + jj;
            int row = inst * 8 + srow;
            int cs = sc_ ^ (row & 7);
            ldsdma16(&As[inst * 512], &A[(m0 + row) * 1024 + k0 + cs * 8]);
        }
#pragma unroll
        for (int jj = 0; jj < 2; ++jj) {
            int inst = w * 2 + jj;
            int row = inst * 8 + srow;
            int cs = sc_ ^ (row & 7);
            ldsdma16(&Bs[inst * 512], &W[(e0 + row) * 1024 + k0 + cs * 8]);
        }
    };

    stage(0, 0);
    stage(1, 1);
    int cur = 0;
    for (int kt = 0; kt < 16; ++kt) {
        if (kt < 14) asm volatile("s_waitcnt vmcnt(4)" ::: "memory");
        else         asm volatile("s_waitcnt vmcnt(0)" ::: "memory");
        __builtin_amdgcn_s_barrier();
        const unsigned short* As = SMEM + cur * 8192;
        const unsigned short* Bs = As + 4096;
#pragma unroll
        for (int kk = 0; kk < 64; kk += 32) {
            const int cb = kk >> 3;
            bf16x8 af[4], bfr;
#pragma unroll
            for (int i = 0; i < 4; ++i) {
                int r = i * 16 + l15;
                af[i] = ld8(&As[r * 64 + (((cb + grp) ^ (r & 7)) << 3)]);
            }
            {
                int r = w * 16 + l15;
                bfr = ld8(&Bs[r * 64 + (((cb + grp) ^ (r & 7)) << 3)]);
            }
            __builtin_amdgcn_s_setprio(1);
#pragma unroll
            for (int i = 0; i < 4; ++i)
                acc[i] = __builtin_amdgcn_mfma_f32_16x16x32_bf16(
                    af[i], bfr, acc[i], 0, 0, 0);
            __builtin_amdgcn_s_setprio(0);
        }
        __builtin_amdgcn_s_barrier();
        if (kt + 2 < 16) stage(cur, kt + 2);
        cur ^= 1;
    }

    {
        int e = e0 + w * 16 + l15;
        float bv_ = bias[e];
#pragma unroll
        for (int i = 0; i < 4; ++i)
#pragma unroll
            for (int r = 0; r < 4; ++r) {
                int jl = (m0 & 2047) + i * 16 + grp * 4 + r;
                if (jl < nbl) {
                    int s = sidx[b * 2048 + jl];
                    out[(size_t)(b * 2048 + s) * 1024 + e] = acc[i][r] + bv_;
                }
            }
    }
}

extern "C" void kernel_launch(void* const* d_in, const int* in_sizes, int n_in,
                              void* d_out, int out_size, void* d_ws, size_t ws_size,
                              hipStream_t stream) {
    const float* x    = (const float*)d_in[0];
    const float* mask = (const float*)d_in[1];
    const float* Wq   = (const float*)d_in[2];
    const float* bq   = (const float*)d_in[3];
    const float* Wk   = (const float*)d_in[4];
    const float* bk   = (const float*)d_in[5];
    const float* Wv   = (const float*)d_in[6];
    const float* bv   = (const float*)d_in[7];
    const float* Wo   = (const float*)d_in[8];
    const float* bo   = (const float*)d_in[9];
    float* out = (float*)d_out;

    unsigned short* Qc   = (unsigned short*)d_ws;    // u16 element offsets:
    unsigned short* Kc   = Qc + 4194304;
    unsigned short* VTc  = Qc + 8388608;
    unsigned short* XcXa = Qc + 12582912;            // Xc (prep->qkv), then Xattn
    unsigned short* Wb   = Qc + 16777216;
    int* sidx            = (int*)(Qc + 20971520);    // 4096 ints
    int* hdr             = sidx + 4096;              // nb[2], nbp[2]

    compact_kernel<<<dim3(4098), 256, 0, stream>>>(mask, Wq, Wk, Wv, Wo,
                                                   sidx, hdr, Wb);
    prep_kernel<<<dim3(4096), 256, 0, stream>>>(x, sidx, hdr, XcXa);
    qkv_kernel<<<dim3(64, 48), 256, 0, stream>>>(XcXa, Wb, bq, bk, bv, hdr,
                                                 Qc, Kc, VTc);
    attn_kernel<<<dim3(16, 32), 512, 0, stream>>>(Qc, Kc, VTc, hdr, XcXa);
    oproj_kernel<<<dim3(5120), 256, 0, stream>>>(XcXa, Wb + 3145728, bo,
                                                 sidx, hdr, mask, out);
}